// Round 1
// baseline (214.060 us; speedup 1.0000x reference)
//
#include <hip/hip_runtime.h>
#include <hip/hip_bf16.h>
#include <cstdint>

// N=2, L=2048, H=8, d=64, D=512. Inputs/outputs f32; features bf16 + MFMA.

typedef __bf16 bf16x8 __attribute__((ext_vector_type(8)));
typedef float f32x16 __attribute__((ext_vector_type(16)));
typedef unsigned short u16x8 __attribute__((ext_vector_type(8)));

__device__ __forceinline__ unsigned short f2bfu(float f) {
    uint32_t u = __float_as_uint(f);
    uint32_t r = (u + 0x7fffu + ((u >> 16) & 1u)) >> 16;
    return (unsigned short)r;
}
__device__ __forceinline__ uint32_t cvt2(float a, float b) {
    __hip_bfloat162 h = __float22bfloat162_rn(make_float2(a, b));
    return *reinterpret_cast<uint32_t*>(&h);
}
__device__ __forceinline__ float softplusf(float x) {
    // fast: log(1+e^-|x|) via __logf; error ~1e-6 rel, far below bf16 ulp.
    return fmaxf(x, 0.f) + __logf(1.f + __expf(-fabsf(x)));
}

// ---------------------------------------------------------------------------
// proj: C[m][c] = X[m][:] . W[c][:]  (4096x512x512), bf16 MFMA, 64x128 tiles,
// register-double-buffered staging. 768 blocks (3/CU). UNCHANGED this round.
// mode 0 -> Af[nh][l][128] bf16; mode 1 -> Bf[nh][l][128]; mode 2 -> Vf[nh][dd][l]
// ---------------------------------------------------------------------------
__global__ __launch_bounds__(256) void proj_kernel(
    const float* __restrict__ query, const float* __restrict__ key,
    const float* __restrict__ Wq, const float* __restrict__ Wk,
    const float* __restrict__ Wv, const float* __restrict__ coef,
    const float* __restrict__ posw, const float* __restrict__ posb,
    unsigned short* __restrict__ Af, unsigned short* __restrict__ Bf,
    unsigned short* __restrict__ Vf)
{
    const int mode = blockIdx.z;
    const int c0 = blockIdx.x * 128;   // 4 tiles
    const int m0 = blockIdx.y * 64;    // 64 tiles
    const float* X = (mode == 0) ? query : key;
    const float* W = (mode == 0) ? Wq : (mode == 1 ? Wk : Wv);

    __shared__ __align__(16) char smem[64 * 72 * 2 + 128 * 72 * 2];  // 27648 B
    unsigned short* Xs = (unsigned short*)smem;                  // [64][72]
    unsigned short* Ws = (unsigned short*)(smem + 64 * 72 * 2);  // [128][72]

    const int t = threadIdx.x;
    const int lane = t & 63, wv = t >> 6;
    const int lm = lane & 31, half = lane >> 5;
    const int wrow = wv >> 1, wcol = wv & 1;

    f32x16 acc[2] = {};

    float4 px[4], pw[8];
    {
#pragma unroll
        for (int it = 0; it < 4; ++it) {
            int cid = t + it * 256, row = cid >> 4, off = (cid & 15) << 2;
            px[it] = *(const float4*)&X[(size_t)(m0 + row) * 512 + off];
        }
#pragma unroll
        for (int it = 0; it < 8; ++it) {
            int cid = t + it * 256, row = cid >> 4, off = (cid & 15) << 2;
            pw[it] = *(const float4*)&W[(size_t)(c0 + row) * 512 + off];
        }
    }

    for (int kt = 0; kt < 8; ++kt) {
        __syncthreads();
#pragma unroll
        for (int it = 0; it < 4; ++it) {
            int cid = t + it * 256, row = cid >> 4, off = (cid & 15) << 2;
            uint2 p = { cvt2(px[it].x, px[it].y), cvt2(px[it].z, px[it].w) };
            *(uint2*)&Xs[row * 72 + off] = p;
        }
#pragma unroll
        for (int it = 0; it < 8; ++it) {
            int cid = t + it * 256, row = cid >> 4, off = (cid & 15) << 2;
            uint2 p = { cvt2(pw[it].x, pw[it].y), cvt2(pw[it].z, pw[it].w) };
            *(uint2*)&Ws[row * 72 + off] = p;
        }
        __syncthreads();
        if (kt < 7) {
            int ko = (kt + 1) * 64;
#pragma unroll
            for (int it = 0; it < 4; ++it) {
                int cid = t + it * 256, row = cid >> 4, off = (cid & 15) << 2;
                px[it] = *(const float4*)&X[(size_t)(m0 + row) * 512 + ko + off];
            }
#pragma unroll
            for (int it = 0; it < 8; ++it) {
                int cid = t + it * 256, row = cid >> 4, off = (cid & 15) << 2;
                pw[it] = *(const float4*)&W[(size_t)(c0 + row) * 512 + ko + off];
            }
        }
        const unsigned short* ab = &Xs[(32 * wrow + lm) * 72 + half * 8];
        const unsigned short* bb = &Ws[(64 * wcol + lm) * 72 + half * 8];
#pragma unroll
        for (int ks = 0; ks < 4; ++ks) {
            bf16x8 a  = *(const bf16x8*)(ab + ks * 16);
            bf16x8 b0 = *(const bf16x8*)(bb + ks * 16);
            bf16x8 b1 = *(const bf16x8*)(bb + 32 * 72 + ks * 16);
            acc[0] = __builtin_amdgcn_mfma_f32_32x32x16_bf16(a, b0, acc[0], 0, 0, 0);
            acc[1] = __builtin_amdgcn_mfma_f32_32x32x16_bf16(a, b1, acc[1], 0, 0, 0);
        }
    }

    if (mode != 2) {
        unsigned short* Feat = (mode == 0) ? Af : Bf;
#pragma unroll
        for (int j = 0; j < 2; ++j)
#pragma unroll
        for (int r = 0; r < 16; ++r) {
            int rl = (r & 3) + 8 * (r >> 2) + 4 * half;
            int m = m0 + 32 * wrow + rl;
            int c = c0 + 64 * wcol + 32 * j + lm;
            int n = m >> 11, l = m & 2047;
            int h = c >> 6, jj = c & 63;
            float ang = (float)l * posw[c] + ((mode == 0) ? posb[c] : 0.f);
            float sn, cs; __sincosf(ang, &sn, &cs);
            float v = softplusf(acc[j][r]);
            if (mode == 1) v *= coef[c];
            size_t base = ((size_t)(n * 8 + h) * 2048 + l) * 128 + jj;
            Feat[base]      = f2bfu(v * cs);
            Feat[base + 64] = f2bfu(v * sn);
        }
    } else {
        // transpose through LDS; tb overlays the contiguous smem block:
        // 4 waves * 32*34 floats = 17408 B <= 27648 B.
        float* tb = (float*)smem;
        float* tbw = tb + wv * (32 * 34);
        __syncthreads();   // all waves done with final MFMA reads of Xs/Ws
#pragma unroll
        for (int j = 0; j < 2; ++j) {
            __syncthreads();
#pragma unroll
            for (int r = 0; r < 16; ++r) {
                int rl = (r & 3) + 8 * (r >> 2) + 4 * half;
                tbw[lm * 34 + rl] = acc[j][r];
            }
            __syncthreads();
            int mb = m0 + 32 * wrow;
            int n = mb >> 11, l0 = mb & 2047;
#pragma unroll
            for (int rep = 0; rep < 16; ++rep) {
                int cl = rep * 2 + half;
                float v = tbw[cl * 34 + lm];
                int c = c0 + 64 * wcol + 32 * j + cl;
                int h = c >> 6, dd = c & 63;
                Vf[((size_t)(n * 8 + h) * 64 + dd) * 2048 + l0 + lm] = f2bfu(v);
            }
        }
    }
}

// ---------------------------------------------------------------------------
// attn: SPLIT-K over k-tile parity -> 1024 blocks (4/CU, 16 waves/CU vs 8).
// Block (parity, qt, nh): handles k-tiles kt = parity, parity+2, ... <= qq.
// Even block stores raw O-partial to out, odd block to opart; z partials to
// z0/z1. norm_kernel combines: out = (o0+o1)/(z0+z1). f32 add of exactly two
// partials is commutative -> deterministic. Per-tile structure unchanged
// except: sacc split into 2 accumulators (breaks 8-deep dependent MFMA
// chain), s_setprio around MFMA clusters (T5), launch_bounds(256,4) caps
// VGPR at 128 so 4 blocks/CU (LDS 36KB*4 = 145KB <= 160KB) co-schedule.
// ---------------------------------------------------------------------------
__global__ __launch_bounds__(256, 4) void attn_kernel(
    const unsigned short* __restrict__ Af, const unsigned short* __restrict__ Bf,
    const unsigned short* __restrict__ Vf, float* __restrict__ out,
    float* __restrict__ opart, float* __restrict__ z0, float* __restrict__ z1)
{
    const int bid = blockIdx.x;
    const int parity = bid >> 9;        // 0: even k-tiles, 1: odd k-tiles
    const int bx = bid & 511;
    const int nh = bx & 15;
    const int p  = bx >> 4;
    const int qq = (p < 16) ? p : 47 - p;   // complementary pairing, both parities
    const int q0 = qq * 64;

    __shared__ unsigned short Bs[64 * 136];   // K-features [k][128+pad]; A-stage at init
    __shared__ unsigned short Ss[64 * 72];    // S tile [q][k+pad] bf16
    __shared__ unsigned short Vs[64 * 72];    // V [dd][k]
    __shared__ float zf[64];

    const int t = threadIdx.x;
    const int lane = t & 63, wv = t >> 6;
    const int lm = lane & 31, half = lane >> 5;
    const int wrow = wv >> 1, wcol = wv & 1;
    const int n = nh >> 3, h = nh & 7;

    const unsigned short* Ah = Af + (size_t)nh * 2048 * 128;
    const unsigned short* Bh = Bf + (size_t)nh * 2048 * 128;
    const unsigned short* Vh = Vf + (size_t)nh * 64 * 2048;

    // stage Q-features through Bs once, pull A-fragments into registers
#pragma unroll
    for (int it = 0; it < 4; ++it) {
        int cid = t + it * 256, row = cid >> 4, off = (cid & 15) << 3;
        *(u16x8*)&Bs[row * 136 + off] = *(const u16x8*)&Ah[(size_t)(q0 + row) * 128 + off];
    }
    if (t < 64) zf[t] = 0.f;
    __syncthreads();
    bf16x8 afrag[8];
    {
        const unsigned short* ab = &Bs[(32 * wrow + lm) * 136 + half * 8];
#pragma unroll
        for (int c = 0; c < 8; ++c) afrag[c] = *(const bf16x8*)(ab + c * 16);
    }

    f32x16 oacc = {};
    float zp[16];
#pragma unroll
    for (int r = 0; r < 16; ++r) zp[r] = 0.f;

    u16x8 pb[4], pv[2];
    {
        const int kbase = parity * 64;
#pragma unroll
        for (int it = 0; it < 4; ++it) {
            int cid = t + it * 256, row = cid >> 4, off = (cid & 15) << 3;
            pb[it] = *(const u16x8*)&Bh[(size_t)(kbase + row) * 128 + off];
        }
#pragma unroll
        for (int it = 0; it < 2; ++it) {
            int cid = t + it * 256, row = cid >> 3, off = (cid & 7) << 3;
            pv[it] = *(const u16x8*)&Vh[(size_t)row * 2048 + kbase + off];
        }
    }

    for (int kt = parity; kt <= qq; kt += 2) {
        __syncthreads();   // b1: afrag reads done (first iter); prev O-reads of Ss/Vs done
#pragma unroll
        for (int it = 0; it < 4; ++it) {
            int cid = t + it * 256, row = cid >> 4, off = (cid & 15) << 3;
            *(u16x8*)&Bs[row * 136 + off] = pb[it];
        }
#pragma unroll
        for (int it = 0; it < 2; ++it) {
            int cid = t + it * 256, row = cid >> 3, off = (cid & 7) << 3;
            *(u16x8*)&Vs[row * 72 + off] = pv[it];
        }
        __syncthreads();   // b2: Bs/Vs visible
        if (kt + 2 <= qq) {
            int k1 = (kt + 2) * 64;
#pragma unroll
            for (int it = 0; it < 4; ++it) {
                int cid = t + it * 256, row = cid >> 4, off = (cid & 15) << 3;
                pb[it] = *(const u16x8*)&Bh[(size_t)(k1 + row) * 128 + off];
            }
#pragma unroll
            for (int it = 0; it < 2; ++it) {
                int cid = t + it * 256, row = cid >> 3, off = (cid & 7) << 3;
                pv[it] = *(const u16x8*)&Vh[(size_t)row * 2048 + k1 + off];
            }
        }

        // S = A . B^T : two independent accumulator chains (4-deep each)
        f32x16 sacc = {}, sacc1 = {};
        const unsigned short* bbase = &Bs[(32 * wcol + lm) * 136 + half * 8];
        __builtin_amdgcn_s_setprio(1);
#pragma unroll
        for (int ks = 0; ks < 8; ks += 2) {
            bf16x8 b0 = *(const bf16x8*)(bbase + ks * 16);
            bf16x8 b1 = *(const bf16x8*)(bbase + (ks + 1) * 16);
            sacc  = __builtin_amdgcn_mfma_f32_32x32x16_bf16(afrag[ks],     b0, sacc,  0, 0, 0);
            sacc1 = __builtin_amdgcn_mfma_f32_32x32x16_bf16(afrag[ks + 1], b1, sacc1, 0, 0, 0);
        }
        __builtin_amdgcn_s_setprio(0);
#pragma unroll
        for (int r = 0; r < 16; ++r) sacc[r] += sacc1[r];

        if (kt == qq) {   // diagonal tile owned only by the block with matching parity
#pragma unroll
            for (int r = 0; r < 16; ++r) {
                int rl = (r & 3) + 8 * (r >> 2) + 4 * half;
                if ((32 * wcol + lm) > (32 * wrow + rl)) sacc[r] = 0.f;
            }
        }
#pragma unroll
        for (int r = 0; r < 16; ++r) zp[r] += fabsf(sacc[r]);

        // writeback S -> Ss (own data; ordered vs prev O-reads by b1/b2)
#pragma unroll
        for (int r = 0; r < 16; ++r) {
            int rl = (r & 3) + 8 * (r >> 2) + 4 * half;
            Ss[(32 * wrow + rl) * 72 + 32 * wcol + lm] = f2bfu(sacc[r]);
        }
        __syncthreads();   // b3: Ss visible

        const unsigned short* sbase = &Ss[(32 * wrow + lm) * 72 + half * 8];
        const unsigned short* vbase = &Vs[(32 * wcol + lm) * 72 + half * 8];
        __builtin_amdgcn_s_setprio(1);
#pragma unroll
        for (int kc = 0; kc < 4; ++kc) {
            bf16x8 a = *(const bf16x8*)(sbase + kc * 16);
            bf16x8 b = *(const bf16x8*)(vbase + kc * 16);
            oacc = __builtin_amdgcn_mfma_f32_32x32x16_bf16(a, b, oacc, 0, 0, 0);
        }
        __builtin_amdgcn_s_setprio(0);
    }

    // reduce z: shuffle over 32-lane halves, then LDS atomics across waves
    __syncthreads();
#pragma unroll
    for (int r = 0; r < 16; ++r) {
        float z = zp[r];
        z += __shfl_xor(z, 1);
        z += __shfl_xor(z, 2);
        z += __shfl_xor(z, 4);
        z += __shfl_xor(z, 8);
        z += __shfl_xor(z, 16);
        if (lm == 0) {
            int rl = (r & 3) + 8 * (r >> 2) + 4 * half;
            atomicAdd(&zf[32 * wrow + rl], z);
        }
    }
    __syncthreads();

    float* zdst = parity ? z1 : z0;
    if (t < 64) zdst[(size_t)nh * 2048 + q0 + t] = zf[t];

    float* dst = parity ? opart : out;
#pragma unroll
    for (int r = 0; r < 16; ++r) {
        int rl = (r & 3) + 8 * (r >> 2) + 4 * half;
        int q = q0 + 32 * wrow + rl;
        dst[((size_t)(n * 2048 + q)) * 512 + h * 64 + 32 * wcol + lm] = oacc[r];
    }
}

// ---------------------------------------------------------------------------
// norm: out = (out_partial_even + opart_odd) / (z0 + z1). 2M f32 elements,
// float4 per thread, 2048 blocks x 256. ~25 MB HBM -> ~4 us.
// ---------------------------------------------------------------------------
__global__ __launch_bounds__(256) void norm_kernel(
    const float* __restrict__ opart, const float* __restrict__ z0,
    const float* __restrict__ z1, float* __restrict__ out)
{
    int idx = blockIdx.x * 256 + threadIdx.x;   // float4 index
    int i = idx << 2;
    int row = i >> 9;          // n*2048 + q
    int c = i & 511;
    int n = row >> 11, q = row & 2047;
    int h = c >> 6;
    size_t zi = (size_t)(n * 8 + h) * 2048 + q;
    float rz = 1.f / (z0[zi] + z1[zi]);
    float4 o = *(const float4*)&out[i];
    float4 pp = *(const float4*)&opart[i];
    float4 r;
    r.x = (o.x + pp.x) * rz;
    r.y = (o.y + pp.y) * rz;
    r.z = (o.z + pp.z) * rz;
    r.w = (o.w + pp.w) * rz;
    *(float4*)&out[i] = r;
}

extern "C" void kernel_launch(void* const* d_in, const int* in_sizes, int n_in,
                              void* d_out, int out_size, void* d_ws, size_t ws_size,
                              hipStream_t stream) {
    (void)in_sizes; (void)n_in; (void)out_size; (void)ws_size;
    const float* query = (const float*)d_in[0];
    const float* key   = (const float*)d_in[1];
    const float* Wq    = (const float*)d_in[2];
    const float* Wk    = (const float*)d_in[3];
    const float* Wv    = (const float*)d_in[4];
    const float* coef  = (const float*)d_in[5];
    const float* posw  = (const float*)d_in[6];
    const float* posb  = (const float*)d_in[7];

    unsigned short* Af = (unsigned short*)d_ws;          // 8 MiB
    unsigned short* Bf = Af + (size_t)16 * 2048 * 128;   // 8 MiB
    unsigned short* Vf = Bf + (size_t)16 * 2048 * 128;   // 4 MiB
    float* opart = (float*)(Vf + (size_t)16 * 64 * 2048);   // 8 MiB (odd-parity O partial)
    float* z0    = opart + (size_t)2 * 2048 * 512;          // 128 KiB
    float* z1    = z0 + (size_t)16 * 2048;                  // 128 KiB
    // total workspace: ~28.3 MiB

    proj_kernel<<<dim3(4, 64, 3), 256, 0, stream>>>(
        query, key, Wq, Wk, Wv, coef, posw, posb, Af, Bf, Vf);
    attn_kernel<<<dim3(1024), 256, 0, stream>>>(
        Af, Bf, Vf, (float*)d_out, opart, z0, z1);
    norm_kernel<<<dim3(2048), 256, 0, stream>>>(
        opart, z0, z1, (float*)d_out);
}

// Round 2
// 140.705 us; speedup vs baseline: 1.5213x; 1.5213x over previous
//
#include <hip/hip_runtime.h>
#include <hip/hip_bf16.h>
#include <cstdint>

// N=2, L=2048, H=8, d=64, D=512. Inputs/outputs f32; features bf16 + MFMA.

typedef __bf16 bf16x8 __attribute__((ext_vector_type(8)));
typedef float f32x16 __attribute__((ext_vector_type(16)));
typedef unsigned short u16x8 __attribute__((ext_vector_type(8)));

__device__ __forceinline__ unsigned short f2bfu(float f) {
    uint32_t u = __float_as_uint(f);
    uint32_t r = (u + 0x7fffu + ((u >> 16) & 1u)) >> 16;
    return (unsigned short)r;
}
__device__ __forceinline__ uint32_t cvt2(float a, float b) {
    __hip_bfloat162 h = __float22bfloat162_rn(make_float2(a, b));
    return *reinterpret_cast<uint32_t*>(&h);
}
__device__ __forceinline__ float softplusf(float x) {
    // fast: log(1+e^-|x|) via __logf; error ~1e-6 rel, far below bf16 ulp.
    return fmaxf(x, 0.f) + __logf(1.f + __expf(-fabsf(x)));
}

// ---------------------------------------------------------------------------
// proj: C[m][c] = X[m][:] . W[c][:]  (4096x512x512), bf16 MFMA, 64x128 tiles,
// register-double-buffered staging. 768 blocks (3/CU). UNCHANGED.
// mode 0 -> Af[nh][l][128] bf16; mode 1 -> Bf[nh][l][128]; mode 2 -> Vf[nh][dd][l]
// ---------------------------------------------------------------------------
__global__ __launch_bounds__(256) void proj_kernel(
    const float* __restrict__ query, const float* __restrict__ key,
    const float* __restrict__ Wq, const float* __restrict__ Wk,
    const float* __restrict__ Wv, const float* __restrict__ coef,
    const float* __restrict__ posw, const float* __restrict__ posb,
    unsigned short* __restrict__ Af, unsigned short* __restrict__ Bf,
    unsigned short* __restrict__ Vf)
{
    const int mode = blockIdx.z;
    const int c0 = blockIdx.x * 128;   // 4 tiles
    const int m0 = blockIdx.y * 64;    // 64 tiles
    const float* X = (mode == 0) ? query : key;
    const float* W = (mode == 0) ? Wq : (mode == 1 ? Wk : Wv);

    __shared__ __align__(16) char smem[64 * 72 * 2 + 128 * 72 * 2];  // 27648 B
    unsigned short* Xs = (unsigned short*)smem;                  // [64][72]
    unsigned short* Ws = (unsigned short*)(smem + 64 * 72 * 2);  // [128][72]

    const int t = threadIdx.x;
    const int lane = t & 63, wv = t >> 6;
    const int lm = lane & 31, half = lane >> 5;
    const int wrow = wv >> 1, wcol = wv & 1;

    f32x16 acc[2] = {};

    float4 px[4], pw[8];
    {
#pragma unroll
        for (int it = 0; it < 4; ++it) {
            int cid = t + it * 256, row = cid >> 4, off = (cid & 15) << 2;
            px[it] = *(const float4*)&X[(size_t)(m0 + row) * 512 + off];
        }
#pragma unroll
        for (int it = 0; it < 8; ++it) {
            int cid = t + it * 256, row = cid >> 4, off = (cid & 15) << 2;
            pw[it] = *(const float4*)&W[(size_t)(c0 + row) * 512 + off];
        }
    }

    for (int kt = 0; kt < 8; ++kt) {
        __syncthreads();
#pragma unroll
        for (int it = 0; it < 4; ++it) {
            int cid = t + it * 256, row = cid >> 4, off = (cid & 15) << 2;
            uint2 p = { cvt2(px[it].x, px[it].y), cvt2(px[it].z, px[it].w) };
            *(uint2*)&Xs[row * 72 + off] = p;
        }
#pragma unroll
        for (int it = 0; it < 8; ++it) {
            int cid = t + it * 256, row = cid >> 4, off = (cid & 15) << 2;
            uint2 p = { cvt2(pw[it].x, pw[it].y), cvt2(pw[it].z, pw[it].w) };
            *(uint2*)&Ws[row * 72 + off] = p;
        }
        __syncthreads();
        if (kt < 7) {
            int ko = (kt + 1) * 64;
#pragma unroll
            for (int it = 0; it < 4; ++it) {
                int cid = t + it * 256, row = cid >> 4, off = (cid & 15) << 2;
                px[it] = *(const float4*)&X[(size_t)(m0 + row) * 512 + ko + off];
            }
#pragma unroll
            for (int it = 0; it < 8; ++it) {
                int cid = t + it * 256, row = cid >> 4, off = (cid & 15) << 2;
                pw[it] = *(const float4*)&W[(size_t)(c0 + row) * 512 + ko + off];
            }
        }
        const unsigned short* ab = &Xs[(32 * wrow + lm) * 72 + half * 8];
        const unsigned short* bb = &Ws[(64 * wcol + lm) * 72 + half * 8];
#pragma unroll
        for (int ks = 0; ks < 4; ++ks) {
            bf16x8 a  = *(const bf16x8*)(ab + ks * 16);
            bf16x8 b0 = *(const bf16x8*)(bb + ks * 16);
            bf16x8 b1 = *(const bf16x8*)(bb + 32 * 72 + ks * 16);
            acc[0] = __builtin_amdgcn_mfma_f32_32x32x16_bf16(a, b0, acc[0], 0, 0, 0);
            acc[1] = __builtin_amdgcn_mfma_f32_32x32x16_bf16(a, b1, acc[1], 0, 0, 0);
        }
    }

    if (mode != 2) {
        unsigned short* Feat = (mode == 0) ? Af : Bf;
#pragma unroll
        for (int j = 0; j < 2; ++j)
#pragma unroll
        for (int r = 0; r < 16; ++r) {
            int rl = (r & 3) + 8 * (r >> 2) + 4 * half;
            int m = m0 + 32 * wrow + rl;
            int c = c0 + 64 * wcol + 32 * j + lm;
            int n = m >> 11, l = m & 2047;
            int h = c >> 6, jj = c & 63;
            float ang = (float)l * posw[c] + ((mode == 0) ? posb[c] : 0.f);
            float sn, cs; __sincosf(ang, &sn, &cs);
            float v = softplusf(acc[j][r]);
            if (mode == 1) v *= coef[c];
            size_t base = ((size_t)(n * 8 + h) * 2048 + l) * 128 + jj;
            Feat[base]      = f2bfu(v * cs);
            Feat[base + 64] = f2bfu(v * sn);
        }
    } else {
        // transpose through LDS; tb overlays the contiguous smem block:
        // 4 waves * 32*34 floats = 17408 B <= 27648 B.
        float* tb = (float*)smem;
        float* tbw = tb + wv * (32 * 34);
        __syncthreads();   // all waves done with final MFMA reads of Xs/Ws
#pragma unroll
        for (int j = 0; j < 2; ++j) {
            __syncthreads();
#pragma unroll
            for (int r = 0; r < 16; ++r) {
                int rl = (r & 3) + 8 * (r >> 2) + 4 * half;
                tbw[lm * 34 + rl] = acc[j][r];
            }
            __syncthreads();
            int mb = m0 + 32 * wrow;
            int n = mb >> 11, l0 = mb & 2047;
#pragma unroll
            for (int rep = 0; rep < 16; ++rep) {
                int cl = rep * 2 + half;
                float v = tbw[cl * 34 + lm];
                int c = c0 + 64 * wcol + 32 * j + cl;
                int h = c >> 6, dd = c & 63;
                Vf[((size_t)(n * 8 + h) * 64 + dd) * 2048 + l0 + lm] = f2bfu(v);
            }
        }
    }
}

// ---------------------------------------------------------------------------
// attn: SPLIT-K over k-tile parity -> 1024 blocks (4/CU target, 16 waves/CU).
// Block (parity, qt, nh): handles k-tiles kt = parity, parity+2, ... <= qq.
// Even block stores raw O-partial to out, odd block to opart; z partials to
// z0/z1. norm_kernel combines: out = (o0+o1)/(z0+z1).
// Round-1 lesson: __launch_bounds__(256,4) + dual-sacc caused VGPR clamp to
// 64 and ~45 MB scratch spill (WRITE_SIZE 8.2->62 MB), 2.7x regression.
// This round: plain launch_bounds(256) (natural alloc was 84 VGPR <= 128 ->
// 4 waves/SIMD bin already), single sacc chain. Occupancy comes from the
// 2x grid alone. setprio kept (free, +4-7% on phase-diverse attn blocks).
// ---------------------------------------------------------------------------
__global__ __launch_bounds__(256) void attn_kernel(
    const unsigned short* __restrict__ Af, const unsigned short* __restrict__ Bf,
    const unsigned short* __restrict__ Vf, float* __restrict__ out,
    float* __restrict__ opart, float* __restrict__ z0, float* __restrict__ z1)
{
    const int bid = blockIdx.x;
    const int parity = bid >> 9;        // 0: even k-tiles, 1: odd k-tiles
    const int bx = bid & 511;
    const int nh = bx & 15;
    const int p  = bx >> 4;
    const int qq = (p < 16) ? p : 47 - p;   // complementary pairing, both parities
    const int q0 = qq * 64;

    __shared__ unsigned short Bs[64 * 136];   // K-features [k][128+pad]; A-stage at init
    __shared__ unsigned short Ss[64 * 72];    // S tile [q][k+pad] bf16
    __shared__ unsigned short Vs[64 * 72];    // V [dd][k]
    __shared__ float zf[64];

    const int t = threadIdx.x;
    const int lane = t & 63, wv = t >> 6;
    const int lm = lane & 31, half = lane >> 5;
    const int wrow = wv >> 1, wcol = wv & 1;
    const int n = nh >> 3, h = nh & 7;

    const unsigned short* Ah = Af + (size_t)nh * 2048 * 128;
    const unsigned short* Bh = Bf + (size_t)nh * 2048 * 128;
    const unsigned short* Vh = Vf + (size_t)nh * 64 * 2048;

    // stage Q-features through Bs once, pull A-fragments into registers
#pragma unroll
    for (int it = 0; it < 4; ++it) {
        int cid = t + it * 256, row = cid >> 4, off = (cid & 15) << 3;
        *(u16x8*)&Bs[row * 136 + off] = *(const u16x8*)&Ah[(size_t)(q0 + row) * 128 + off];
    }
    if (t < 64) zf[t] = 0.f;
    __syncthreads();
    bf16x8 afrag[8];
    {
        const unsigned short* ab = &Bs[(32 * wrow + lm) * 136 + half * 8];
#pragma unroll
        for (int c = 0; c < 8; ++c) afrag[c] = *(const bf16x8*)(ab + c * 16);
    }

    f32x16 oacc = {};
    float zp[16];
#pragma unroll
    for (int r = 0; r < 16; ++r) zp[r] = 0.f;

    u16x8 pb[4], pv[2];
    {
        const int kbase = parity * 64;
#pragma unroll
        for (int it = 0; it < 4; ++it) {
            int cid = t + it * 256, row = cid >> 4, off = (cid & 15) << 3;
            pb[it] = *(const u16x8*)&Bh[(size_t)(kbase + row) * 128 + off];
        }
#pragma unroll
        for (int it = 0; it < 2; ++it) {
            int cid = t + it * 256, row = cid >> 3, off = (cid & 7) << 3;
            pv[it] = *(const u16x8*)&Vh[(size_t)row * 2048 + kbase + off];
        }
    }

    for (int kt = parity; kt <= qq; kt += 2) {
        __syncthreads();   // b1: afrag reads done (first iter); prev O-reads of Ss/Vs done
#pragma unroll
        for (int it = 0; it < 4; ++it) {
            int cid = t + it * 256, row = cid >> 4, off = (cid & 15) << 3;
            *(u16x8*)&Bs[row * 136 + off] = pb[it];
        }
#pragma unroll
        for (int it = 0; it < 2; ++it) {
            int cid = t + it * 256, row = cid >> 3, off = (cid & 7) << 3;
            *(u16x8*)&Vs[row * 72 + off] = pv[it];
        }
        __syncthreads();   // b2: Bs/Vs visible
        if (kt + 2 <= qq) {
            int k1 = (kt + 2) * 64;
#pragma unroll
            for (int it = 0; it < 4; ++it) {
                int cid = t + it * 256, row = cid >> 4, off = (cid & 15) << 3;
                pb[it] = *(const u16x8*)&Bh[(size_t)(k1 + row) * 128 + off];
            }
#pragma unroll
            for (int it = 0; it < 2; ++it) {
                int cid = t + it * 256, row = cid >> 3, off = (cid & 7) << 3;
                pv[it] = *(const u16x8*)&Vh[(size_t)row * 2048 + k1 + off];
            }
        }

        // S = A . B^T
        f32x16 sacc = {};
        const unsigned short* bbase = &Bs[(32 * wcol + lm) * 136 + half * 8];
        __builtin_amdgcn_s_setprio(1);
#pragma unroll
        for (int ks = 0; ks < 8; ++ks) {
            bf16x8 b = *(const bf16x8*)(bbase + ks * 16);
            sacc = __builtin_amdgcn_mfma_f32_32x32x16_bf16(afrag[ks], b, sacc, 0, 0, 0);
        }
        __builtin_amdgcn_s_setprio(0);

        if (kt == qq) {   // diagonal tile owned only by the block with matching parity
#pragma unroll
            for (int r = 0; r < 16; ++r) {
                int rl = (r & 3) + 8 * (r >> 2) + 4 * half;
                if ((32 * wcol + lm) > (32 * wrow + rl)) sacc[r] = 0.f;
            }
        }
#pragma unroll
        for (int r = 0; r < 16; ++r) zp[r] += fabsf(sacc[r]);

        // writeback S -> Ss (own data; ordered vs prev O-reads by b1/b2)
#pragma unroll
        for (int r = 0; r < 16; ++r) {
            int rl = (r & 3) + 8 * (r >> 2) + 4 * half;
            Ss[(32 * wrow + rl) * 72 + 32 * wcol + lm] = f2bfu(sacc[r]);
        }
        __syncthreads();   // b3: Ss visible

        const unsigned short* sbase = &Ss[(32 * wrow + lm) * 72 + half * 8];
        const unsigned short* vbase = &Vs[(32 * wcol + lm) * 72 + half * 8];
        __builtin_amdgcn_s_setprio(1);
#pragma unroll
        for (int kc = 0; kc < 4; ++kc) {
            bf16x8 a = *(const bf16x8*)(sbase + kc * 16);
            bf16x8 b = *(const bf16x8*)(vbase + kc * 16);
            oacc = __builtin_amdgcn_mfma_f32_32x32x16_bf16(a, b, oacc, 0, 0, 0);
        }
        __builtin_amdgcn_s_setprio(0);
    }

    // reduce z: shuffle over 32-lane halves, then LDS atomics across waves
    __syncthreads();
#pragma unroll
    for (int r = 0; r < 16; ++r) {
        float z = zp[r];
        z += __shfl_xor(z, 1);
        z += __shfl_xor(z, 2);
        z += __shfl_xor(z, 4);
        z += __shfl_xor(z, 8);
        z += __shfl_xor(z, 16);
        if (lm == 0) {
            int rl = (r & 3) + 8 * (r >> 2) + 4 * half;
            atomicAdd(&zf[32 * wrow + rl], z);
        }
    }
    __syncthreads();

    float* zdst = parity ? z1 : z0;
    if (t < 64) zdst[(size_t)nh * 2048 + q0 + t] = zf[t];

    float* dst = parity ? opart : out;
#pragma unroll
    for (int r = 0; r < 16; ++r) {
        int rl = (r & 3) + 8 * (r >> 2) + 4 * half;
        int q = q0 + 32 * wrow + rl;
        dst[((size_t)(n * 2048 + q)) * 512 + h * 64 + 32 * wcol + lm] = oacc[r];
    }
}

// ---------------------------------------------------------------------------
// norm: out = (out_partial_even + opart_odd) / (z0 + z1). 2M f32 elements,
// float4 per thread, 2048 blocks x 256. ~25 MB HBM -> ~4 us.
// ---------------------------------------------------------------------------
__global__ __launch_bounds__(256) void norm_kernel(
    const float* __restrict__ opart, const float* __restrict__ z0,
    const float* __restrict__ z1, float* __restrict__ out)
{
    int idx = blockIdx.x * 256 + threadIdx.x;   // float4 index
    int i = idx << 2;
    int row = i >> 9;          // n*2048 + q
    int c = i & 511;
    int n = row >> 11, q = row & 2047;
    int h = c >> 6;
    size_t zi = (size_t)(n * 8 + h) * 2048 + q;
    float rz = 1.f / (z0[zi] + z1[zi]);
    float4 o = *(const float4*)&out[i];
    float4 pp = *(const float4*)&opart[i];
    float4 r;
    r.x = (o.x + pp.x) * rz;
    r.y = (o.y + pp.y) * rz;
    r.z = (o.z + pp.z) * rz;
    r.w = (o.w + pp.w) * rz;
    *(float4*)&out[i] = r;
}

extern "C" void kernel_launch(void* const* d_in, const int* in_sizes, int n_in,
                              void* d_out, int out_size, void* d_ws, size_t ws_size,
                              hipStream_t stream) {
    (void)in_sizes; (void)n_in; (void)out_size; (void)ws_size;
    const float* query = (const float*)d_in[0];
    const float* key   = (const float*)d_in[1];
    const float* Wq    = (const float*)d_in[2];
    const float* Wk    = (const float*)d_in[3];
    const float* Wv    = (const float*)d_in[4];
    const float* coef  = (const float*)d_in[5];
    const float* posw  = (const float*)d_in[6];
    const float* posb  = (const float*)d_in[7];

    unsigned short* Af = (unsigned short*)d_ws;          // 8 MiB
    unsigned short* Bf = Af + (size_t)16 * 2048 * 128;   // 8 MiB
    unsigned short* Vf = Bf + (size_t)16 * 2048 * 128;   // 4 MiB
    float* opart = (float*)(Vf + (size_t)16 * 64 * 2048);   // 8 MiB (odd-parity O partial)
    float* z0    = opart + (size_t)2 * 2048 * 512;          // 128 KiB
    float* z1    = z0 + (size_t)16 * 2048;                  // 128 KiB
    // total workspace: ~28.3 MiB

    proj_kernel<<<dim3(4, 64, 3), 256, 0, stream>>>(
        query, key, Wq, Wk, Wv, coef, posw, posb, Af, Bf, Vf);
    attn_kernel<<<dim3(1024), 256, 0, stream>>>(
        Af, Bf, Vf, (float*)d_out, opart, z0, z1);
    norm_kernel<<<dim3(2048), 256, 0, stream>>>(
        opart, z0, z1, (float*)d_out);
}